// Round 16
// baseline (181.350 us; speedup 1.0000x reference)
//
#include <hip/hip_runtime.h>
#include <hip/hip_bf16.h>

#define DIM 256
#define MEMN 2048
#define NROWS 65536
#define KVB 32
#define NT 64            // MEMN / KVB
#define TILE_B 32768     // bytes per blob tile (K 16KB + V 16KB)
#define PART_B 16384     // bytes per K-part / V-part

typedef __bf16 bf16x8 __attribute__((ext_vector_type(8)));
typedef float f32x4 __attribute__((ext_vector_type(4)));
typedef float f32x16 __attribute__((ext_vector_type(16)));
typedef unsigned int uint32x4 __attribute__((ext_vector_type(4)));

// ---------------------------------------------------------------------------
// Prep A (fused): blocks [0,64) build the pre-swizzled K/V blob tile;
// blocks [64,128) compute coords partial sums. One launch instead of two.
//
// Blob tile t (32768 B):
//   K part elems [0,8192): (kv 0..31, x 0..255) holds K[kt+kv][x ^ (kv<<3)]
//   V part elems [8192,16384): rows R 0..63 of 128 elems:
//       L = j ^ ((R&15)<<3); d = 4R + (L>>5); slot = L&31;
//       kv = sigma(slot) = (slot&3) + 8*((slot>>2)&1) + 4*((slot>>3)&1)
//                          + 16*(slot>>4)
//   (sigma matches the 32x32 MFMA C/D register order of P, so PV needs no
//    cross-lane P exchange.)
// ---------------------------------------------------------------------------
__global__ void prep_fused_kernel(const float* __restrict__ mem,
                                  __bf16* __restrict__ blob,
                                  const float* __restrict__ coords,
                                  float* __restrict__ partial) {
    __shared__ __bf16 ltile[KVB][DIM]; // 16 KB (also covers the 2KB red[])
    int t = threadIdx.x;
    if (blockIdx.x >= NT) {
        // ---- coords partial sums ----
        float* red = (float*)&ltile[0][0];
        int b = blockIdx.x - NT;
        const f32x4* src = reinterpret_cast<const f32x4*>(coords + (size_t)b * 2048);
        f32x4 v0 = src[t * 2];
        f32x4 v1 = src[t * 2 + 1];
        red[t]       = v0[0] + v0[2] + v1[0] + v1[2];
        red[256 + t] = v0[1] + v0[3] + v1[1] + v1[3];
        __syncthreads();
        for (int s = 128; s > 0; s >>= 1) {
            if (t < s) { red[t] += red[t + s]; red[256 + t] += red[256 + t + s]; }
            __syncthreads();
        }
        if (t == 0) { partial[b] = red[0]; partial[64 + b] = red[256]; }
        return;
    }
    // ---- blob tile ----
    int tile = blockIdx.x;
    int kt = tile * KVB;
    for (int c = t; c < 1024; c += 256) {
        int e = c * 8, row = e >> 8, col = e & 255;
        const float* s = mem + (size_t)(kt + row) * DIM + col;
        f32x4 a = *reinterpret_cast<const f32x4*>(s);
        f32x4 b = *reinterpret_cast<const f32x4*>(s + 4);
        bf16x8 o;
        #pragma unroll
        for (int j = 0; j < 4; ++j) { o[j] = (__bf16)a[j]; o[j + 4] = (__bf16)b[j]; }
        *reinterpret_cast<bf16x8*>(&ltile[row][col]) = o;
    }
    __syncthreads();
    __bf16* kb = blob + (size_t)tile * 16384;
    __bf16* vb = kb + 8192;
    for (int c = t; c < 1024; c += 256) {
        int e = c * 8, kv = e >> 8, x0 = e & 255;
        bf16x8 o = *reinterpret_cast<const bf16x8*>(&ltile[kv][x0 ^ (kv << 3)]);
        *reinterpret_cast<bf16x8*>(kb + e) = o;
    }
    for (int c = t; c < 1024; c += 256) {
        int idx = c * 8, R = idx >> 7, j0 = idx & 127;
        int L0 = j0 ^ ((R & 15) << 3);
        int d  = 4 * R + (L0 >> 5);
        int hh = (L0 >> 3) & 1;
        int ks = (L0 >> 4) & 1;
        int kvb = 4 * hh + 16 * ks;
        bf16x8 o;
        #pragma unroll
        for (int j = 0; j < 8; ++j) o[j] = ltile[kvb + (j & 3) + 8 * (j >> 2)][d];
        *reinterpret_cast<bf16x8*>(vb + idx) = o;
    }
}

// ---------------------------------------------------------------------------
// Prep B: reduce partials -> mean -> 2-layer MLP -> spatial_emb[256]
// ---------------------------------------------------------------------------
__global__ void prep_emb_kernel(const float* __restrict__ partial,
                                const float* __restrict__ w1,
                                const float* __restrict__ b1,
                                const float* __restrict__ w2,
                                const float* __restrict__ b2,
                                float* __restrict__ emb) {
    __shared__ float red[128];
    __shared__ float h[DIM];
    int t = threadIdx.x; // 256
    if (t < 128) red[t] = partial[t];
    __syncthreads();
    for (int s = 32; s > 0; s >>= 1) {
        if (t < s) { red[t] += red[t + s]; red[64 + t] += red[64 + t + s]; }
        __syncthreads();
    }
    float mx = red[0] * (1.0f / NROWS);
    float my = red[64] * (1.0f / NROWS);
    float hv = mx * w1[2 * t] + my * w1[2 * t + 1] + b1[t];
    h[t] = hv > 0.f ? hv : 0.f;
    __syncthreads();
    float acc = b2[t];
    const float* wr = w2 + (size_t)t * DIM;
    #pragma unroll 4
    for (int k = 0; k < DIM; k += 4) {
        f32x4 wv = *reinterpret_cast<const f32x4*>(wr + k);
        acc += h[k] * wv[0] + h[k + 1] * wv[1] + h[k + 2] * wv[2] + h[k + 3] * wv[3];
    }
    emb[t] = acc;
}

// ---------------------------------------------------------------------------
__device__ __forceinline__ void gload_lds16(const void* g, void* l) {
    __builtin_amdgcn_global_load_lds(
        (const __attribute__((address_space(1))) unsigned int*)g,
        (__attribute__((address_space(3))) unsigned int*)l,
        16, 0, 0);
}

__device__ __forceinline__ unsigned int pkbf(float a, float b) {
    union { __bf16 h; unsigned short u; } ua, ub;
    ua.h = (__bf16)a; ub.h = (__bf16)b;
    return (unsigned int)ua.u | ((unsigned int)ub.u << 16);
}

__device__ __forceinline__ float fexp2(float x) {
#if __has_builtin(__builtin_amdgcn_exp2f)
    return __builtin_amdgcn_exp2f(x);
#else
    return exp2f(x);
#endif
}

// ---------------------------------------------------------------------------
// Flash attention (R14 best-known schedule + R16 PV accumulator-RAW fix).
// 256 thr = 4 waves x 32 q rows = 128 q/block; grid = 512 (2 blocks/CU,
// LDS 80 KB each). Fixed-shift exp2 softmax (shift folded into the single
// QKT accumulator init). One barrier per iteration; K dbuf + V tbuf staging
// issued at iteration top into dead slots; vmcnt(4) bottom. Depth-2 rolling
// ds_read->MFMA register prefetch inside the fully interleaved QKT||PV
// cluster. R16: the pb1 PV stream is offset by 4 output tiles, so each o[j]
// accumulator is touched 8 MFMA instructions (~256 SIMD cyc) apart instead
// of 2 — removes the per-pair MFMA RAW stall (accumulation commutes).
//
// 32x32x16 bf16 layouts (m74/m101):
//   A: row = lane&31, k = 8*(lane>>5)+i
//   B: col = lane&31, k = 8*(lane>>5)+i
//   C/D: col = lane&31, row = (reg&3) + 8*(reg>>2) + 4*(lane>>5)
// ---------------------------------------------------------------------------
__global__ __launch_bounds__(256, 2)
void flash_kernel(const float* __restrict__ feat,
                  const float* __restrict__ emb,
                  const __bf16* __restrict__ blob,
                  float* __restrict__ out) {
    __shared__ char smem[5 * PART_B]; // 80 KB: K0 K1 V0 V1 V2

    const int t = threadIdx.x;
    const int w = t >> 6;
    const int lane = t & 63;
    const int ln = lane & 31;
    const int hi = lane >> 5;

    const int qrow = blockIdx.x * 128 + w * 32 + ln;

    // ---- Q B-frags, scaled by (1/16)*log2(e) for exp2-domain softmax ----
    const float QS = 0.0901684463f;
    bf16x8 qf[16];
    {
        const float* frow = feat + (size_t)qrow * DIM;
        #pragma unroll
        for (int kd = 0; kd < 16; ++kd) {
            int d0 = kd * 16 + hi * 8;
            f32x4 a = *reinterpret_cast<const f32x4*>(frow + d0);
            f32x4 b = *reinterpret_cast<const f32x4*>(frow + d0 + 4);
            f32x4 ea = *reinterpret_cast<const f32x4*>(emb + d0);
            f32x4 eb = *reinterpret_cast<const f32x4*>(emb + d0 + 4);
            bf16x8 q;
            #pragma unroll
            for (int i = 0; i < 4; ++i) {
                q[i]     = (__bf16)((a[i] + ea[i]) * QS);
                q[i + 4] = (__bf16)((b[i] + eb[i]) * QS);
            }
            qf[kd] = q;
        }
    }

    f32x16 o[8];
    #pragma unroll
    for (int dt = 0; dt < 8; ++dt) o[dt] = (f32x16)(0.f);
    float l = 0.f;

    char* kA = smem;                 // stage target / prologue K(0)
    char* kB = smem + PART_B;        // QKT source (K(kt+1))
    char* vA = smem + 2 * PART_B;    // PV source (V(kt))
    char* vB = smem + 3 * PART_B;    // V(kt+1)
    char* vC = smem + 4 * PART_B;    // stage target (V(kt+2))

    f32x16 sa;          // single QKT accumulator (carries the -14 shift)
    bf16x8 pb0, pb1;    // packed P fragments for the two PV k-steps

    // per-wave 4 KB slice of a 16 KB part: 4 x 1KB loads
    #define STAGE_K(k, buf)                                                   \
        {   const char* _g = (const char*)blob + (size_t)(k) * TILE_B         \
                             + w * 4096 + lane * 16;                          \
            char* _d = (buf) + w * 4096;                                      \
            _Pragma("unroll")                                                 \
            for (int _j = 0; _j < 4; ++_j)                                    \
                gload_lds16(_g + _j * 1024, _d + _j * 1024);                  \
        }
    #define STAGE_V(k, buf)                                                   \
        {   const char* _g = (const char*)blob + (size_t)(k) * TILE_B         \
                             + PART_B + w * 4096 + lane * 16;                 \
            char* _d = (buf) + w * 4096;                                      \
            _Pragma("unroll")                                                 \
            for (int _j = 0; _j < 4; ++_j)                                    \
                gload_lds16(_g + _j * 1024, _d + _j * 1024);                  \
        }

    #define KFRAG(buf, kd) \
        (*reinterpret_cast<const bf16x8*>((buf) + ln * 512 + ((((kd) * 16 + hi * 8) ^ (ln * 8)) << 1)))

    #define VFRAG(buf, dt, ks)                                                   \
        (*reinterpret_cast<const bf16x8*>((buf) +                                \
            ((dt) * 8 + (ln >> 2)) * 256 +                                       \
            (((((ln & 3) * 32 + (ks) * 16 + hi * 8)) ^ ((((dt) * 8 + (ln >> 2)) & 15) << 3)) << 1)))

    // fixed-shift softmax on sa: exp2, accumulate l into la, leave packing
    // to the caller (sunk after the barrier).
    #define SOFTMAX_EXP(S, LA)                                                   \
        {   LA = 0.f;                                                            \
            _Pragma("unroll")                                                    \
            for (int _e = 0; _e < 16; ++_e) {                                    \
                float _p = fexp2(sa[_e]);                                        \
                (S)[_e] = _p;                                                    \
                LA += _p;                                                        \
            }                                                                    \
        }
    #define SOFTMAX_PACK(S, LA)                                                  \
        {   l += LA;                                                             \
            uint32x4 _f0, _f1;                                                   \
            _f0[0] = pkbf((S)[0], (S)[1]);   _f0[1] = pkbf((S)[2], (S)[3]);      \
            _f0[2] = pkbf((S)[4], (S)[5]);   _f0[3] = pkbf((S)[6], (S)[7]);      \
            _f1[0] = pkbf((S)[8], (S)[9]);   _f1[1] = pkbf((S)[10], (S)[11]);    \
            _f1[2] = pkbf((S)[12], (S)[13]); _f1[3] = pkbf((S)[14], (S)[15]);    \
            pb0 = __builtin_bit_cast(bf16x8, _f0);                               \
            pb1 = __builtin_bit_cast(bf16x8, _f1);                               \
        }

    // ---- prologue: stage K(0),K(1),V(0),V(1); full drain (safe); QKT(0) ----
    STAGE_K(0, kA);
    STAGE_K(1, kB);
    STAGE_V(0, vA);
    STAGE_V(1, vB);
    asm volatile("s_waitcnt vmcnt(0)" ::: "memory");
    __builtin_amdgcn_s_barrier();
    asm volatile("" ::: "memory");
    sa = (f32x16)(-14.0f);
    __builtin_amdgcn_s_setprio(1);
    #pragma unroll
    for (int i = 0; i < 16; ++i) {
        sa = __builtin_amdgcn_mfma_f32_32x32x16_bf16(KFRAG(kA, i), qf[i], sa, 0, 0, 0);
    }
    __builtin_amdgcn_s_setprio(0);
    {
        f32x16 s0; float la0;
        SOFTMAX_EXP(s0, la0);
        asm volatile("" ::: "memory");
        __builtin_amdgcn_s_barrier();   // all waves done reading kA
        asm volatile("" ::: "memory");
        SOFTMAX_PACK(s0, la0);
    }

    // ---- main loop: one barrier per iteration ----
    #pragma unroll 1
    for (int kt = 0; kt < NT - 1; ++kt) {
        // stage into dead slots: kA (K(kt) read last iter), vC (read two
        // clusters ago)
        if (kt + 2 < NT) {
            STAGE_K(kt + 2, kA);
            STAGE_V(kt + 2, vC);
        }

        // CLUSTER: PV(kt, vA) || QKT(kt+1, kB), interleaved, depth-2 rolling
        // prefetch. pb1 stream offset by 4 tiles: o[j] RAW distance = 8 MFMAs.
        sa = (f32x16)(-14.0f);
        bf16x8 fA = KFRAG(kB, 0);
        bf16x8 fB = VFRAG(vA, 0, 0);
        __builtin_amdgcn_s_setprio(1);
        #pragma unroll
        for (int i = 0; i < 8; ++i) {
            bf16x8 gA = KFRAG(kB, 2 * i + 1);
            bf16x8 gB = VFRAG(vA, (i + 4) & 7, 1);
            sa   = __builtin_amdgcn_mfma_f32_32x32x16_bf16(fA, qf[2 * i], sa, 0, 0, 0);
            o[i] = __builtin_amdgcn_mfma_f32_32x32x16_bf16(fB, pb0, o[i], 0, 0, 0);
            if (i < 7) {
                fA = KFRAG(kB, 2 * i + 2);
                fB = VFRAG(vA, i + 1, 0);
            }
            sa = __builtin_amdgcn_mfma_f32_32x32x16_bf16(gA, qf[2 * i + 1], sa, 0, 0, 0);
            o[(i + 4) & 7] = __builtin_amdgcn_mfma_f32_32x32x16_bf16(
                gB, pb1, o[(i + 4) & 7], 0, 0, 0);
        }
        __builtin_amdgcn_s_setprio(0);

        // softmax(kt+1) exp2 phase — pure VALU, covers the staging loads
        f32x16 sx; float la;
        SOFTMAX_EXP(sx, la);

        // K(kt+2) (and V(kt+1), issued last iter) must be complete; V(kt+2)
        // may stay in flight across the barrier.
        if (kt + 2 < NT) {
            asm volatile("s_waitcnt vmcnt(4)" ::: "memory");
        } else {
            asm volatile("s_waitcnt vmcnt(0)" ::: "memory");
        }
        __builtin_amdgcn_s_barrier();
        asm volatile("" ::: "memory");

        // pb packing sunk after the barrier (reg-only; consumed next iter)
        SOFTMAX_PACK(sx, la);

        // rotate: K swap; V cyclic (vA <- vB <- vC <- vA)
        char* ktmp = kA; kA = kB; kB = ktmp;
        char* vtmp = vA; vA = vB; vB = vC; vC = vtmp;
    }

    // ---- tail: PV(NT-1) from vA; two separate passes (no back-to-back RAW) ----
    __builtin_amdgcn_s_setprio(1);
    #pragma unroll
    for (int i = 0; i < 8; ++i) {
        o[i] = __builtin_amdgcn_mfma_f32_32x32x16_bf16(VFRAG(vA, i, 0), pb0, o[i], 0, 0, 0);
    }
    #pragma unroll
    for (int i = 0; i < 8; ++i) {
        o[i] = __builtin_amdgcn_mfma_f32_32x32x16_bf16(VFRAG(vA, i, 1), pb1, o[i], 0, 0, 0);
    }
    __builtin_amdgcn_s_setprio(0);

    // ---- epilogue: merge l halves, coalesced stores via LDS ----
    l += __shfl_xor(l, 32);
    float linv = 1.f / l;
    __syncthreads();
    #pragma unroll 1
    for (int ph = 0; ph < 2; ++ph) {
        if ((w >> 1) == ph) {
            char* base = smem + ((w & 1) * 32 + ln) * 1024;
            const int sw = (ln & 7) << 4;
            #pragma unroll
            for (int dt = 0; dt < 8; ++dt) {
                #pragma unroll
                for (int g = 0; g < 4; ++g) {
                    f32x4 v;
                    v[0] = o[dt][4 * g + 0] * linv;
                    v[1] = o[dt][4 * g + 1] * linv;
                    v[2] = o[dt][4 * g + 2] * linv;
                    v[3] = o[dt][4 * g + 3] * linv;
                    *reinterpret_cast<f32x4*>(base + ((dt * 128 + g * 32 + hi * 16) ^ sw)) = v;
                }
            }
        }
        __syncthreads();
        {
            char* gdst = (char*)out + ((size_t)blockIdx.x * 128 + ph * 64) * 1024;
            #pragma unroll
            for (int i = 0; i < 16; ++i) {
                int bo = t * 16 + i * 4096;
                int r = bo >> 10, off = bo & 1023;
                f32x4 v = *reinterpret_cast<const f32x4*>(
                    smem + r * 1024 + (off ^ ((r & 7) << 4)));
                *reinterpret_cast<f32x4*>(gdst + (size_t)r * 1024 + off) = v;
            }
        }
        __syncthreads();
    }
    #undef STAGE_K
    #undef STAGE_V
    #undef KFRAG
    #undef VFRAG
    #undef SOFTMAX_EXP
    #undef SOFTMAX_PACK
}

// ---------------------------------------------------------------------------
extern "C" void kernel_launch(void* const* d_in, const int* in_sizes, int n_in,
                              void* d_out, int out_size, void* d_ws, size_t ws_size,
                              hipStream_t stream) {
    const float* features = (const float*)d_in[0];
    const float* coords   = (const float*)d_in[1];
    const float* memory   = (const float*)d_in[2];
    const float* w1       = (const float*)d_in[3];
    const float* b1       = (const float*)d_in[4];
    const float* w2       = (const float*)d_in[5];
    const float* b2       = (const float*)d_in[6];
    float* out = (float*)d_out;

    // ws: partial[128]f @0 | emb[256]f @512B | blob 2MiB @2048B
    float*  partial = (float*)d_ws;
    float*  emb     = (float*)((char*)d_ws + 512);
    __bf16* blob    = (__bf16*)((char*)d_ws + 2048);

    prep_fused_kernel<<<NT + 64, 256, 0, stream>>>(memory, blob, coords, partial);
    prep_emb_kernel<<<1, 256, 0, stream>>>(partial, w1, b1, w2, b2, emb);
    flash_kernel<<<NROWS / 128, 256, 0, stream>>>(features, emb, blob, out);
}

// Round 17
// 173.486 us; speedup vs baseline: 1.0453x; 1.0453x over previous
//
#include <hip/hip_runtime.h>
#include <hip/hip_bf16.h>

#define DIM 256
#define MEMN 2048
#define NROWS 65536
#define KVB 32
#define NT 64            // MEMN / KVB
#define TILE_B 32768     // bytes per blob tile (K 16KB + V 16KB)
#define PART_B 16384     // bytes per K-part / V-part

typedef __bf16 bf16x8 __attribute__((ext_vector_type(8)));
typedef float f32x4 __attribute__((ext_vector_type(4)));
typedef float f32x16 __attribute__((ext_vector_type(16)));
typedef unsigned int uint32x4 __attribute__((ext_vector_type(4)));

// ---------------------------------------------------------------------------
// Prep A (fused): blocks [0,64) build the pre-swizzled K/V blob tile;
// blocks [64,128) compute coords partial sums. One launch instead of two.
//
// Blob tile t (32768 B):
//   K part elems [0,8192): (kv 0..31, x 0..255) holds K[kt+kv][x ^ (kv<<3)]
//   V part elems [8192,16384): rows R 0..63 of 128 elems:
//       L = j ^ ((R&15)<<3); d = 4R + (L>>5); slot = L&31;
//       kv = sigma(slot) = (slot&3) + 8*((slot>>2)&1) + 4*((slot>>3)&1)
//                          + 16*(slot>>4)
//   (sigma matches the 32x32 MFMA C/D register order of P, so PV needs no
//    cross-lane P exchange.)
// ---------------------------------------------------------------------------
__global__ void prep_fused_kernel(const float* __restrict__ mem,
                                  __bf16* __restrict__ blob,
                                  const float* __restrict__ coords,
                                  float* __restrict__ partial) {
    __shared__ __bf16 ltile[KVB][DIM]; // 16 KB (also covers the 2KB red[])
    int t = threadIdx.x;
    if (blockIdx.x >= NT) {
        // ---- coords partial sums ----
        float* red = (float*)&ltile[0][0];
        int b = blockIdx.x - NT;
        const f32x4* src = reinterpret_cast<const f32x4*>(coords + (size_t)b * 2048);
        f32x4 v0 = src[t * 2];
        f32x4 v1 = src[t * 2 + 1];
        red[t]       = v0[0] + v0[2] + v1[0] + v1[2];
        red[256 + t] = v0[1] + v0[3] + v1[1] + v1[3];
        __syncthreads();
        for (int s = 128; s > 0; s >>= 1) {
            if (t < s) { red[t] += red[t + s]; red[256 + t] += red[256 + t + s]; }
            __syncthreads();
        }
        if (t == 0) { partial[b] = red[0]; partial[64 + b] = red[256]; }
        return;
    }
    // ---- blob tile ----
    int tile = blockIdx.x;
    int kt = tile * KVB;
    for (int c = t; c < 1024; c += 256) {
        int e = c * 8, row = e >> 8, col = e & 255;
        const float* s = mem + (size_t)(kt + row) * DIM + col;
        f32x4 a = *reinterpret_cast<const f32x4*>(s);
        f32x4 b = *reinterpret_cast<const f32x4*>(s + 4);
        bf16x8 o;
        #pragma unroll
        for (int j = 0; j < 4; ++j) { o[j] = (__bf16)a[j]; o[j + 4] = (__bf16)b[j]; }
        *reinterpret_cast<bf16x8*>(&ltile[row][col]) = o;
    }
    __syncthreads();
    __bf16* kb = blob + (size_t)tile * 16384;
    __bf16* vb = kb + 8192;
    for (int c = t; c < 1024; c += 256) {
        int e = c * 8, kv = e >> 8, x0 = e & 255;
        bf16x8 o = *reinterpret_cast<const bf16x8*>(&ltile[kv][x0 ^ (kv << 3)]);
        *reinterpret_cast<bf16x8*>(kb + e) = o;
    }
    for (int c = t; c < 1024; c += 256) {
        int idx = c * 8, R = idx >> 7, j0 = idx & 127;
        int L0 = j0 ^ ((R & 15) << 3);
        int d  = 4 * R + (L0 >> 5);
        int hh = (L0 >> 3) & 1;
        int ks = (L0 >> 4) & 1;
        int kvb = 4 * hh + 16 * ks;
        bf16x8 o;
        #pragma unroll
        for (int j = 0; j < 8; ++j) o[j] = ltile[kvb + (j & 3) + 8 * (j >> 2)][d];
        *reinterpret_cast<bf16x8*>(vb + idx) = o;
    }
}

// ---------------------------------------------------------------------------
// Prep B: reduce partials -> mean -> 2-layer MLP -> spatial_emb[256]
// ---------------------------------------------------------------------------
__global__ void prep_emb_kernel(const float* __restrict__ partial,
                                const float* __restrict__ w1,
                                const float* __restrict__ b1,
                                const float* __restrict__ w2,
                                const float* __restrict__ b2,
                                float* __restrict__ emb) {
    __shared__ float red[128];
    __shared__ float h[DIM];
    int t = threadIdx.x; // 256
    if (t < 128) red[t] = partial[t];
    __syncthreads();
    for (int s = 32; s > 0; s >>= 1) {
        if (t < s) { red[t] += red[t + s]; red[64 + t] += red[64 + t + s]; }
        __syncthreads();
    }
    float mx = red[0] * (1.0f / NROWS);
    float my = red[64] * (1.0f / NROWS);
    float hv = mx * w1[2 * t] + my * w1[2 * t + 1] + b1[t];
    h[t] = hv > 0.f ? hv : 0.f;
    __syncthreads();
    float acc = b2[t];
    const float* wr = w2 + (size_t)t * DIM;
    #pragma unroll 4
    for (int k = 0; k < DIM; k += 4) {
        f32x4 wv = *reinterpret_cast<const f32x4*>(wr + k);
        acc += h[k] * wv[0] + h[k + 1] * wv[1] + h[k + 2] * wv[2] + h[k + 3] * wv[3];
    }
    emb[t] = acc;
}

// ---------------------------------------------------------------------------
__device__ __forceinline__ void gload_lds16(const void* g, void* l) {
    __builtin_amdgcn_global_load_lds(
        (const __attribute__((address_space(1))) unsigned int*)g,
        (__attribute__((address_space(3))) unsigned int*)l,
        16, 0, 0);
}

__device__ __forceinline__ unsigned int pkbf(float a, float b) {
    union { __bf16 h; unsigned short u; } ua, ub;
    ua.h = (__bf16)a; ub.h = (__bf16)b;
    return (unsigned int)ua.u | ((unsigned int)ub.u << 16);
}

__device__ __forceinline__ float fexp2(float x) {
#if __has_builtin(__builtin_amdgcn_exp2f)
    return __builtin_amdgcn_exp2f(x);
#else
    return exp2f(x);
#endif
}

// ---------------------------------------------------------------------------
// Flash attention (R14 best-known configuration, restored).
// 256 thr = 4 waves x 32 q rows = 128 q/block; grid = 512 (2 blocks/CU,
// LDS 80 KB each). Fixed-shift exp2 softmax (shift folded into the single
// QKT accumulator init). One barrier per iteration; K dbuf + V tbuf staging
// issued at iteration top into dead slots; vmcnt(4) bottom. Depth-2 rolling
// ds_read->MFMA register prefetch inside the fully interleaved QKT||PV
// cluster; softmax exp2 after the cluster; pb-pack sunk after the barrier.
//
// 32x32x16 bf16 layouts (m74/m101):
//   A: row = lane&31, k = 8*(lane>>5)+i
//   B: col = lane&31, k = 8*(lane>>5)+i
//   C/D: col = lane&31, row = (reg&3) + 8*(reg>>2) + 4*(lane>>5)
// ---------------------------------------------------------------------------
__global__ __launch_bounds__(256, 2)
void flash_kernel(const float* __restrict__ feat,
                  const float* __restrict__ emb,
                  const __bf16* __restrict__ blob,
                  float* __restrict__ out) {
    __shared__ char smem[5 * PART_B]; // 80 KB: K0 K1 V0 V1 V2

    const int t = threadIdx.x;
    const int w = t >> 6;
    const int lane = t & 63;
    const int ln = lane & 31;
    const int hi = lane >> 5;

    const int qrow = blockIdx.x * 128 + w * 32 + ln;

    // ---- Q B-frags, scaled by (1/16)*log2(e) for exp2-domain softmax ----
    const float QS = 0.0901684463f;
    bf16x8 qf[16];
    {
        const float* frow = feat + (size_t)qrow * DIM;
        #pragma unroll
        for (int kd = 0; kd < 16; ++kd) {
            int d0 = kd * 16 + hi * 8;
            f32x4 a = *reinterpret_cast<const f32x4*>(frow + d0);
            f32x4 b = *reinterpret_cast<const f32x4*>(frow + d0 + 4);
            f32x4 ea = *reinterpret_cast<const f32x4*>(emb + d0);
            f32x4 eb = *reinterpret_cast<const f32x4*>(emb + d0 + 4);
            bf16x8 q;
            #pragma unroll
            for (int i = 0; i < 4; ++i) {
                q[i]     = (__bf16)((a[i] + ea[i]) * QS);
                q[i + 4] = (__bf16)((b[i] + eb[i]) * QS);
            }
            qf[kd] = q;
        }
    }

    f32x16 o[8];
    #pragma unroll
    for (int dt = 0; dt < 8; ++dt) o[dt] = (f32x16)(0.f);
    float l = 0.f;

    char* kA = smem;                 // stage target / prologue K(0)
    char* kB = smem + PART_B;        // QKT source (K(kt+1))
    char* vA = smem + 2 * PART_B;    // PV source (V(kt))
    char* vB = smem + 3 * PART_B;    // V(kt+1)
    char* vC = smem + 4 * PART_B;    // stage target (V(kt+2))

    f32x16 sa;          // single QKT accumulator (carries the -14 shift)
    bf16x8 pb0, pb1;    // packed P fragments for the two PV k-steps

    // per-wave 4 KB slice of a 16 KB part: 4 x 1KB loads
    #define STAGE_K(k, buf)                                                   \
        {   const char* _g = (const char*)blob + (size_t)(k) * TILE_B         \
                             + w * 4096 + lane * 16;                          \
            char* _d = (buf) + w * 4096;                                      \
            _Pragma("unroll")                                                 \
            for (int _j = 0; _j < 4; ++_j)                                    \
                gload_lds16(_g + _j * 1024, _d + _j * 1024);                  \
        }
    #define STAGE_V(k, buf)                                                   \
        {   const char* _g = (const char*)blob + (size_t)(k) * TILE_B         \
                             + PART_B + w * 4096 + lane * 16;                 \
            char* _d = (buf) + w * 4096;                                      \
            _Pragma("unroll")                                                 \
            for (int _j = 0; _j < 4; ++_j)                                    \
                gload_lds16(_g + _j * 1024, _d + _j * 1024);                  \
        }

    #define KFRAG(buf, kd) \
        (*reinterpret_cast<const bf16x8*>((buf) + ln * 512 + ((((kd) * 16 + hi * 8) ^ (ln * 8)) << 1)))

    #define VFRAG(buf, dt, ks)                                                   \
        (*reinterpret_cast<const bf16x8*>((buf) +                                \
            ((dt) * 8 + (ln >> 2)) * 256 +                                       \
            (((((ln & 3) * 32 + (ks) * 16 + hi * 8)) ^ ((((dt) * 8 + (ln >> 2)) & 15) << 3)) << 1)))

    // fixed-shift softmax on sa: exp2, accumulate l into la, leave packing
    // to the caller (sunk after the barrier).
    #define SOFTMAX_EXP(S, LA)                                                   \
        {   LA = 0.f;                                                            \
            _Pragma("unroll")                                                    \
            for (int _e = 0; _e < 16; ++_e) {                                    \
                float _p = fexp2(sa[_e]);                                        \
                (S)[_e] = _p;                                                    \
                LA += _p;                                                        \
            }                                                                    \
        }
    #define SOFTMAX_PACK(S, LA)                                                  \
        {   l += LA;                                                             \
            uint32x4 _f0, _f1;                                                   \
            _f0[0] = pkbf((S)[0], (S)[1]);   _f0[1] = pkbf((S)[2], (S)[3]);      \
            _f0[2] = pkbf((S)[4], (S)[5]);   _f0[3] = pkbf((S)[6], (S)[7]);      \
            _f1[0] = pkbf((S)[8], (S)[9]);   _f1[1] = pkbf((S)[10], (S)[11]);    \
            _f1[2] = pkbf((S)[12], (S)[13]); _f1[3] = pkbf((S)[14], (S)[15]);    \
            pb0 = __builtin_bit_cast(bf16x8, _f0);                               \
            pb1 = __builtin_bit_cast(bf16x8, _f1);                               \
        }

    // ---- prologue: stage K(0),K(1),V(0),V(1); full drain (safe); QKT(0) ----
    STAGE_K(0, kA);
    STAGE_K(1, kB);
    STAGE_V(0, vA);
    STAGE_V(1, vB);
    asm volatile("s_waitcnt vmcnt(0)" ::: "memory");
    __builtin_amdgcn_s_barrier();
    asm volatile("" ::: "memory");
    sa = (f32x16)(-14.0f);
    __builtin_amdgcn_s_setprio(1);
    #pragma unroll
    for (int i = 0; i < 16; ++i) {
        sa = __builtin_amdgcn_mfma_f32_32x32x16_bf16(KFRAG(kA, i), qf[i], sa, 0, 0, 0);
    }
    __builtin_amdgcn_s_setprio(0);
    {
        f32x16 s0; float la0;
        SOFTMAX_EXP(s0, la0);
        asm volatile("" ::: "memory");
        __builtin_amdgcn_s_barrier();   // all waves done reading kA
        asm volatile("" ::: "memory");
        SOFTMAX_PACK(s0, la0);
    }

    // ---- main loop: one barrier per iteration ----
    #pragma unroll 1
    for (int kt = 0; kt < NT - 1; ++kt) {
        // stage into dead slots: kA (K(kt) read last iter), vC (read two
        // clusters ago)
        if (kt + 2 < NT) {
            STAGE_K(kt + 2, kA);
            STAGE_V(kt + 2, vC);
        }

        // CLUSTER: PV(kt, vA) || QKT(kt+1, kB), interleaved, with rolling
        // 2-frag register prefetch (each ds_read issued >=2 MFMAs before use).
        sa = (f32x16)(-14.0f);
        bf16x8 fA = KFRAG(kB, 0);
        bf16x8 fB = VFRAG(vA, 0, 0);
        __builtin_amdgcn_s_setprio(1);
        #pragma unroll
        for (int i = 0; i < 8; ++i) {
            bf16x8 gA = KFRAG(kB, 2 * i + 1);
            bf16x8 gB = VFRAG(vA, i, 1);
            sa   = __builtin_amdgcn_mfma_f32_32x32x16_bf16(fA, qf[2 * i], sa, 0, 0, 0);
            o[i] = __builtin_amdgcn_mfma_f32_32x32x16_bf16(fB, pb0, o[i], 0, 0, 0);
            if (i < 7) {
                fA = KFRAG(kB, 2 * i + 2);
                fB = VFRAG(vA, i + 1, 0);
            }
            sa   = __builtin_amdgcn_mfma_f32_32x32x16_bf16(gA, qf[2 * i + 1], sa, 0, 0, 0);
            o[i] = __builtin_amdgcn_mfma_f32_32x32x16_bf16(gB, pb1, o[i], 0, 0, 0);
        }
        __builtin_amdgcn_s_setprio(0);

        // softmax(kt+1) exp2 phase — pure VALU, covers the staging loads
        f32x16 sx; float la;
        SOFTMAX_EXP(sx, la);

        // K(kt+2) (and V(kt+1), issued last iter) must be complete; V(kt+2)
        // may stay in flight across the barrier.
        if (kt + 2 < NT) {
            asm volatile("s_waitcnt vmcnt(4)" ::: "memory");
        } else {
            asm volatile("s_waitcnt vmcnt(0)" ::: "memory");
        }
        __builtin_amdgcn_s_barrier();
        asm volatile("" ::: "memory");

        // pb packing sunk after the barrier (reg-only; consumed next iter)
        SOFTMAX_PACK(sx, la);

        // rotate: K swap; V cyclic (vA <- vB <- vC <- vA)
        char* ktmp = kA; kA = kB; kB = ktmp;
        char* vtmp = vA; vA = vB; vB = vC; vC = vtmp;
    }

    // ---- tail: PV(NT-1) from vA ----
    __builtin_amdgcn_s_setprio(1);
    #pragma unroll
    for (int i = 0; i < 8; ++i) {
        o[i] = __builtin_amdgcn_mfma_f32_32x32x16_bf16(VFRAG(vA, i, 0), pb0, o[i], 0, 0, 0);
        o[i] = __builtin_amdgcn_mfma_f32_32x32x16_bf16(VFRAG(vA, i, 1), pb1, o[i], 0, 0, 0);
    }
    __builtin_amdgcn_s_setprio(0);

    // ---- epilogue: merge l halves, coalesced stores via LDS ----
    l += __shfl_xor(l, 32);
    float linv = 1.f / l;
    __syncthreads();
    #pragma unroll 1
    for (int ph = 0; ph < 2; ++ph) {
        if ((w >> 1) == ph) {
            char* base = smem + ((w & 1) * 32 + ln) * 1024;
            const int sw = (ln & 7) << 4;
            #pragma unroll
            for (int dt = 0; dt < 8; ++dt) {
                #pragma unroll
                for (int g = 0; g < 4; ++g) {
                    f32x4 v;
                    v[0] = o[dt][4 * g + 0] * linv;
                    v[1] = o[dt][4 * g + 1] * linv;
                    v[2] = o[dt][4 * g + 2] * linv;
                    v[3] = o[dt][4 * g + 3] * linv;
                    *reinterpret_cast<f32x4*>(base + ((dt * 128 + g * 32 + hi * 16) ^ sw)) = v;
                }
            }
        }
        __syncthreads();
        {
            char* gdst = (char*)out + ((size_t)blockIdx.x * 128 + ph * 64) * 1024;
            #pragma unroll
            for (int i = 0; i < 16; ++i) {
                int bo = t * 16 + i * 4096;
                int r = bo >> 10, off = bo & 1023;
                f32x4 v = *reinterpret_cast<const f32x4*>(
                    smem + r * 1024 + (off ^ ((r & 7) << 4)));
                *reinterpret_cast<f32x4*>(gdst + (size_t)r * 1024 + off) = v;
            }
        }
        __syncthreads();
    }
    #undef STAGE_K
    #undef STAGE_V
    #undef KFRAG
    #undef VFRAG
    #undef SOFTMAX_EXP
    #undef SOFTMAX_PACK
}

// ---------------------------------------------------------------------------
extern "C" void kernel_launch(void* const* d_in, const int* in_sizes, int n_in,
                              void* d_out, int out_size, void* d_ws, size_t ws_size,
                              hipStream_t stream) {
    const float* features = (const float*)d_in[0];
    const float* coords   = (const float*)d_in[1];
    const float* memory   = (const float*)d_in[2];
    const float* w1       = (const float*)d_in[3];
    const float* b1       = (const float*)d_in[4];
    const float* w2       = (const float*)d_in[5];
    const float* b2       = (const float*)d_in[6];
    float* out = (float*)d_out;

    // ws: partial[128]f @0 | emb[256]f @512B | blob 2MiB @2048B
    float*  partial = (float*)d_ws;
    float*  emb     = (float*)((char*)d_ws + 512);
    __bf16* blob    = (__bf16*)((char*)d_ws + 2048);

    prep_fused_kernel<<<NT + 64, 256, 0, stream>>>(memory, blob, coords, partial);
    prep_emb_kernel<<<1, 256, 0, stream>>>(partial, w1, b1, w2, b2, emb);
    flash_kernel<<<NROWS / 128, 256, 0, stream>>>(features, emb, blob, out);
}